// Round 6
// baseline (50.517 us; speedup 1.0000x reference)
//
#include <hip/hip_runtime.h>

#define NMOL 256
#define VSH 264   // ushort stride, sv hi/lo planes (32 rows x 256 k)
#define TS  40    // ushort stride, shT planes (256 cols x 32 nodes) and adjacency

typedef short bf16x8 __attribute__((ext_vector_type(8)));
typedef float f32x4  __attribute__((ext_vector_type(4)));

__device__ __forceinline__ unsigned short bf_trunc(float f) {
    return (unsigned short)(__float_as_uint(f) >> 16);
}
__device__ __forceinline__ float bf_hif(float f) {
    return __uint_as_float(__float_as_uint(f) & 0xFFFF0000u);
}
__device__ __forceinline__ unsigned short bf_rne(float f) {
    unsigned int u = __float_as_uint(f);
    return (unsigned short)((u + 0x7FFFu + ((u >> 16) & 1u)) >> 16);
}

// split 8 fp32 (two float4) into bf16 hi (trunc) / lo (rne residual) fragments
__device__ __forceinline__ void split8(float4 a, float4 b, bf16x8& hi, bf16x8& lo) {
    float v0[4] = {a.x, a.y, a.z, a.w};
    float v1[4] = {b.x, b.y, b.z, b.w};
    union { unsigned int u[4]; bf16x8 s; } H, L;
    #pragma unroll
    for (int i = 0; i < 2; ++i) {
        unsigned int u0 = __float_as_uint(v0[2*i]), u1 = __float_as_uint(v0[2*i+1]);
        H.u[i] = (u0 >> 16) | (u1 & 0xFFFF0000u);
        unsigned int l0 = bf_rne(v0[2*i]   - __uint_as_float(u0 & 0xFFFF0000u));
        unsigned int l1 = bf_rne(v0[2*i+1] - __uint_as_float(u1 & 0xFFFF0000u));
        L.u[i] = l0 | (l1 << 16);
    }
    #pragma unroll
    for (int i = 0; i < 2; ++i) {
        unsigned int u0 = __float_as_uint(v1[2*i]), u1 = __float_as_uint(v1[2*i+1]);
        H.u[2+i] = (u0 >> 16) | (u1 & 0xFFFF0000u);
        unsigned int l0 = bf_rne(v1[2*i]   - __uint_as_float(u0 & 0xFFFF0000u));
        unsigned int l1 = bf_rne(v1[2*i+1] - __uint_as_float(u1 & 0xFFFF0000u));
        L.u[2+i] = l0 | (l1 << 16);
    }
    hi = H.s; lo = L.s;
}

// ---------------- main kernel: gather + 3 GNN layers + pool -> gmol ----------------
__launch_bounds__(512, 2)
__global__ void molgnn_layers(const int* __restrict__ subgraph,
                              const float* __restrict__ adj,
                              const float* __restrict__ emb,
                              const float* __restrict__ w_sub,
                              const float* __restrict__ b_sub,
                              float* __restrict__ gmol) {
    __shared__ unsigned short svh[32 * VSH];   // v hi plane  [row][k]
    __shared__ unsigned short svl[32 * VSH];   // v lo plane
    __shared__ unsigned short sth[256 * TS];   // h^T hi plane [col][node]
    __shared__ unsigned short stl[256 * TS];   // h^T lo plane
    __shared__ unsigned short sah[32 * TS];    // adjacency block bf16 (exact 0/1)
    __shared__ float srow[8 * 32];
    __shared__ float sinv[32];
    __shared__ float sbias[3 * 256];

    const int t = threadIdx.x, m = blockIdx.x;
    const int w  = t >> 6;          // wave 0..7 -> col slab of 32
    const int l  = t & 63;
    const int lr = l & 15;          // frag row/col index
    const int lg = l >> 4;          // frag k-group
    const int j0 = w * 32;

    // W fragment bases (fp32 plane): rows (j0+jt*16+lr), k-offset lg*8
    int bfr[2];
    bfr[0] = (j0 + lr) * 256 + lg * 8;
    bfr[1] = (j0 + 16 + lr) * 256 + lg * 8;

    // ---- early prefetch: layer-0 kt=0 raw fp32 W fragments ----
    float4 Bva[2][2], Bvb[2][2];
    #pragma unroll
    for (int jt = 0; jt < 2; ++jt) {
        Bva[0][jt] = *(const float4*)(w_sub + bfr[jt]);
        Bvb[0][jt] = *(const float4*)(w_sub + bfr[jt] + 4);
    }

    // stage hidden biases
    for (int i = t; i < 768; i += 512) sbias[i] = b_sub[i];

    // gather emb rows -> sv hi/lo planes (16 elems per thread)
    {
        const int r = t >> 4, c0 = (t & 15) * 16;
        const float* src = emb + (long)subgraph[m * 32 + r] * 256 + c0;
        #pragma unroll
        for (int q = 0; q < 16; q += 4) {
            float4 v = *(const float4*)(src + q);
            unsigned int h01 = (unsigned int)bf_trunc(v.x) | ((unsigned int)bf_trunc(v.y) << 16);
            unsigned int h23 = (unsigned int)bf_trunc(v.z) | ((unsigned int)bf_trunc(v.w) << 16);
            unsigned int l01 = (unsigned int)bf_rne(v.x - bf_hif(v.x)) | ((unsigned int)bf_rne(v.y - bf_hif(v.y)) << 16);
            unsigned int l23 = (unsigned int)bf_rne(v.z - bf_hif(v.z)) | ((unsigned int)bf_rne(v.w - bf_hif(v.w)) << 16);
            *(uint2*)&svh[r * VSH + c0 + q] = make_uint2(h01, h23);
            *(uint2*)&svl[r * VSH + c0 + q] = make_uint2(l01, l23);
        }
    }
    // adjacency diag block -> bf16 (0/1 exact under truncation)
    {
        const int r = t >> 4, p0 = (t & 15) * 2;
        const float* ar = adj + (long)(m * 32 + r) * 8192 + m * 32 + p0;
        float2 a = *(const float2*)ar;
        sah[r * TS + p0 + 0] = bf_trunc(a.x);
        sah[r * TS + p0 + 1] = bf_trunc(a.y);
    }
    __syncthreads();

    f32x4 acc[2][2];   // [mt][jt]

    for (int layer = 0; layer < 3; ++layer) {
        // C init = bias[col], broadcast over rows
        #pragma unroll
        for (int jt = 0; jt < 2; ++jt) {
            float b = sbias[layer * 256 + j0 + jt * 16 + lr];
            #pragma unroll
            for (int mt = 0; mt < 2; ++mt) {
                acc[mt][jt][0] = b; acc[mt][jt][1] = b; acc[mt][jt][2] = b; acc[mt][jt][3] = b;
            }
        }

        const float* WP = w_sub + layer * 65536;
        const int nl = (layer < 2) ? layer + 1 : 0;   // layer 2 wraps harmlessly
        const float* WPn = w_sub + nl * 65536;

        // GEMM1: h = v @ W^T  (split bf16, 3 products); raw fp32 W double-buffered,
        // hi/lo split done in-register
        #pragma unroll
        for (int kt = 0; kt < 8; ++kt) {
            const int cur = kt & 1, nxt = cur ^ 1;
            if (kt < 7) {
                #pragma unroll
                for (int jt = 0; jt < 2; ++jt) {
                    Bva[nxt][jt] = *(const float4*)(WP + bfr[jt] + (kt + 1) * 32);
                    Bvb[nxt][jt] = *(const float4*)(WP + bfr[jt] + (kt + 1) * 32 + 4);
                }
            } else {
                #pragma unroll
                for (int jt = 0; jt < 2; ++jt) {
                    Bva[nxt][jt] = *(const float4*)(WPn + bfr[jt]);
                    Bvb[nxt][jt] = *(const float4*)(WPn + bfr[jt] + 4);
                }
            }
            bf16x8 Bh[2], Bl[2];
            #pragma unroll
            for (int jt = 0; jt < 2; ++jt) split8(Bva[cur][jt], Bvb[cur][jt], Bh[jt], Bl[jt]);
            bf16x8 Ah[2], Al[2];
            #pragma unroll
            for (int mt = 0; mt < 2; ++mt) {
                int off = (mt * 16 + lr) * VSH + kt * 32 + lg * 8;
                Ah[mt] = *(const bf16x8*)&svh[off];
                Al[mt] = *(const bf16x8*)&svl[off];
            }
            #pragma unroll
            for (int mt = 0; mt < 2; ++mt)
                #pragma unroll
                for (int jt = 0; jt < 2; ++jt) {
                    acc[mt][jt] = __builtin_amdgcn_mfma_f32_16x16x32_bf16(Ah[mt], Bh[jt], acc[mt][jt], 0, 0, 0);
                    acc[mt][jt] = __builtin_amdgcn_mfma_f32_16x16x32_bf16(Al[mt], Bh[jt], acc[mt][jt], 0, 0, 0);
                    acc[mt][jt] = __builtin_amdgcn_mfma_f32_16x16x32_bf16(Ah[mt], Bl[jt], acc[mt][jt], 0, 0, 0);
                }
        }

        // relu; stage h^T (hi/lo) for this wave's own 32-col slab (no cross-wave use)
        #pragma unroll
        for (int mt = 0; mt < 2; ++mt)
            #pragma unroll
            for (int jt = 0; jt < 2; ++jt) {
                int col = j0 + jt * 16 + lr;
                float hv[4];
                #pragma unroll
                for (int r = 0; r < 4; ++r) {
                    float h = fmaxf(acc[mt][jt][r], 0.f);
                    acc[mt][jt][r] = h;              // residual stays in C
                    hv[r] = h;
                }
                ushort4 hp, lp;
                hp.x = bf_trunc(hv[0]); hp.y = bf_trunc(hv[1]); hp.z = bf_trunc(hv[2]); hp.w = bf_trunc(hv[3]);
                lp.x = bf_rne(hv[0] - bf_hif(hv[0])); lp.y = bf_rne(hv[1] - bf_hif(hv[1]));
                lp.z = bf_rne(hv[2] - bf_hif(hv[2])); lp.w = bf_rne(hv[3] - bf_hif(hv[3]));
                int off = col * TS + mt * 16 + lg * 4;
                *(ushort4*)&sth[off] = hp;
                *(ushort4*)&stl[off] = lp;
            }

        // GEMM2: acc += A @ h  (A exact bf16; h split -> 2 products). Same-wave LDS, no barrier.
        {
            bf16x8 Aa[2];
            #pragma unroll
            for (int mt = 0; mt < 2; ++mt)
                Aa[mt] = *(const bf16x8*)&sah[(mt * 16 + lr) * TS + lg * 8];
            #pragma unroll
            for (int jt = 0; jt < 2; ++jt) {
                int off = (j0 + jt * 16 + lr) * TS + lg * 8;
                bf16x8 Hh = *(const bf16x8*)&sth[off];
                bf16x8 Hl = *(const bf16x8*)&stl[off];
                #pragma unroll
                for (int mt = 0; mt < 2; ++mt) {
                    acc[mt][jt] = __builtin_amdgcn_mfma_f32_16x16x32_bf16(Aa[mt], Hh, acc[mt][jt], 0, 0, 0);
                    acc[mt][jt] = __builtin_amdgcn_mfma_f32_16x16x32_bf16(Aa[mt], Hl, acc[mt][jt], 0, 0, 0);
                }
            }
        }

        // row L2 normalize (rows = mt*16 + lg*4 + r; cols split across lr-lanes and 8 waves)
        float ss[2][4];
        #pragma unroll
        for (int mt = 0; mt < 2; ++mt)
            #pragma unroll
            for (int r = 0; r < 4; ++r) {
                float s = 0.f;
                #pragma unroll
                for (int jt = 0; jt < 2; ++jt) { float a = acc[mt][jt][r]; s += a * a; }
                s += __shfl_xor(s, 1); s += __shfl_xor(s, 2);
                s += __shfl_xor(s, 4); s += __shfl_xor(s, 8);
                ss[mt][r] = s;
            }
        if (lr == 0) {
            #pragma unroll
            for (int mt = 0; mt < 2; ++mt)
                #pragma unroll
                for (int r = 0; r < 4; ++r)
                    srow[w * 32 + mt * 16 + lg * 4 + r] = ss[mt][r];
        }
        __syncthreads();
        if (t < 32) {
            float s = 0.f;
            #pragma unroll
            for (int ww = 0; ww < 8; ++ww) s += srow[ww * 32 + t];
            sinv[t] = 1.0f / fmaxf(sqrtf(s), 1e-12f);
        }
        __syncthreads();
        #pragma unroll
        for (int mt = 0; mt < 2; ++mt)
            #pragma unroll
            for (int r = 0; r < 4; ++r) {
                float iv = sinv[mt * 16 + lg * 4 + r];
                #pragma unroll
                for (int jt = 0; jt < 2; ++jt) acc[mt][jt][r] *= iv;
            }

        if (layer < 2) {
            // write normalized v back as next layer's A planes
            #pragma unroll
            for (int mt = 0; mt < 2; ++mt)
                #pragma unroll
                for (int jt = 0; jt < 2; ++jt) {
                    int col = j0 + jt * 16 + lr;
                    #pragma unroll
                    for (int r = 0; r < 4; ++r) {
                        int row = mt * 16 + lg * 4 + r;
                        float vv = acc[mt][jt][r];
                        svh[row * VSH + col] = bf_trunc(vv);
                        svl[row * VSH + col] = bf_rne(vv - bf_hif(vv));
                    }
                }
            __syncthreads();
        }
    }

    // sum-pool per molecule -> gmol[m][col] (each wave owns its 32 cols)
    #pragma unroll
    for (int jt = 0; jt < 2; ++jt) {
        float s = 0.f;
        #pragma unroll
        for (int mt = 0; mt < 2; ++mt)
            #pragma unroll
            for (int r = 0; r < 4; ++r) s += acc[mt][jt][r];
        s += __shfl_xor(s, 16);
        s += __shfl_xor(s, 32);
        if (l < 16) gmol[m * 256 + j0 + jt * 16 + l] = s;
    }
}

// ---------------- tail kernel: 16 molecules/block, out-MLP (MFMA) + head ----------------
__launch_bounds__(512, 1)
__global__ void molgnn_tail(const float* __restrict__ gmol,
                            const float* __restrict__ w_out,
                            const float* __restrict__ b_out,
                            const float* __restrict__ w_prop,
                            const float* __restrict__ b_prop,
                            float* __restrict__ out) {
    __shared__ unsigned short pxh[16 * VSH];   // x hi plane [row][k], 16 molecule rows
    __shared__ unsigned short pxl[16 * VSH];   // x lo plane
    __shared__ float sred[8 * 16];

    const int t = threadIdx.x, mb = blockIdx.x;   // mb: 16-molecule group
    const int w  = t >> 6;
    const int l  = t & 63;
    const int lr = l & 15;
    const int lg = l >> 4;
    const int j0 = w * 32;

    int bfr[2];
    bfr[0] = (j0 + lr) * 256 + lg * 8;
    bfr[1] = (j0 + 16 + lr) * 256 + lg * 8;

    // early prefetch: layer-0 kt=0 W fragments
    float4 Bva[2][2], Bvb[2][2];
    #pragma unroll
    for (int jt = 0; jt < 2; ++jt) {
        Bva[0][jt] = *(const float4*)(w_out + bfr[jt]);
        Bvb[0][jt] = *(const float4*)(w_out + bfr[jt] + 4);
    }

    // stage mol rows -> x hi/lo planes (8 elems per thread)
    {
        const int r = t >> 5, c0 = (t & 31) * 8;
        const float* src = gmol + (long)(mb * 16 + r) * 256 + c0;
        #pragma unroll
        for (int q = 0; q < 8; q += 4) {
            float4 v = *(const float4*)(src + q);
            unsigned int h01 = (unsigned int)bf_trunc(v.x) | ((unsigned int)bf_trunc(v.y) << 16);
            unsigned int h23 = (unsigned int)bf_trunc(v.z) | ((unsigned int)bf_trunc(v.w) << 16);
            unsigned int l01 = (unsigned int)bf_rne(v.x - bf_hif(v.x)) | ((unsigned int)bf_rne(v.y - bf_hif(v.y)) << 16);
            unsigned int l23 = (unsigned int)bf_rne(v.z - bf_hif(v.z)) | ((unsigned int)bf_rne(v.w - bf_hif(v.w)) << 16);
            *(uint2*)&pxh[r * VSH + c0 + q] = make_uint2(h01, h23);
            *(uint2*)&pxl[r * VSH + c0 + q] = make_uint2(l01, l23);
        }
    }
    __syncthreads();

    f32x4 acc[2];   // [jt], 16 rows (mt absent)

    for (int layer = 0; layer < 2; ++layer) {
        #pragma unroll
        for (int jt = 0; jt < 2; ++jt) {
            float b = b_out[layer * 256 + j0 + jt * 16 + lr];
            acc[jt][0] = b; acc[jt][1] = b; acc[jt][2] = b; acc[jt][3] = b;
        }

        const float* WP = w_out + layer * 65536;
        const float* WPn = w_out + (layer ^ 1) * 65536;   // next (wraps harmlessly)

        #pragma unroll
        for (int kt = 0; kt < 8; ++kt) {
            const int cur = kt & 1, nxt = cur ^ 1;
            if (kt < 7) {
                #pragma unroll
                for (int jt = 0; jt < 2; ++jt) {
                    Bva[nxt][jt] = *(const float4*)(WP + bfr[jt] + (kt + 1) * 32);
                    Bvb[nxt][jt] = *(const float4*)(WP + bfr[jt] + (kt + 1) * 32 + 4);
                }
            } else {
                #pragma unroll
                for (int jt = 0; jt < 2; ++jt) {
                    Bva[nxt][jt] = *(const float4*)(WPn + bfr[jt]);
                    Bvb[nxt][jt] = *(const float4*)(WPn + bfr[jt] + 4);
                }
            }
            bf16x8 Bh[2], Bl[2];
            #pragma unroll
            for (int jt = 0; jt < 2; ++jt) split8(Bva[cur][jt], Bvb[cur][jt], Bh[jt], Bl[jt]);
            int off = lr * VSH + kt * 32 + lg * 8;
            bf16x8 Ah = *(const bf16x8*)&pxh[off];
            bf16x8 Al = *(const bf16x8*)&pxl[off];
            #pragma unroll
            for (int jt = 0; jt < 2; ++jt) {
                acc[jt] = __builtin_amdgcn_mfma_f32_16x16x32_bf16(Ah, Bh[jt], acc[jt], 0, 0, 0);
                acc[jt] = __builtin_amdgcn_mfma_f32_16x16x32_bf16(Al, Bh[jt], acc[jt], 0, 0, 0);
                acc[jt] = __builtin_amdgcn_mfma_f32_16x16x32_bf16(Ah, Bl[jt], acc[jt], 0, 0, 0);
            }
        }

        // relu
        #pragma unroll
        for (int jt = 0; jt < 2; ++jt)
            #pragma unroll
            for (int r = 0; r < 4; ++r)
                acc[jt][r] = fmaxf(acc[jt][r], 0.f);

        if (layer == 0) {
            // write x back to planes for layer 1 (rows = lg*4+r, col = j0+jt*16+lr)
            __syncthreads();   // all waves done reading planes
            #pragma unroll
            for (int jt = 0; jt < 2; ++jt) {
                int col = j0 + jt * 16 + lr;
                #pragma unroll
                for (int r = 0; r < 4; ++r) {
                    int row = lg * 4 + r;
                    float vv = acc[jt][r];
                    pxh[row * VSH + col] = bf_trunc(vv);
                    pxl[row * VSH + col] = bf_rne(vv - bf_hif(vv));
                }
            }
            __syncthreads();
        }
    }

    // head: out[row] = sum_col x[row][col] * w_prop[col] + b_prop
    {
        float part[4] = {0.f, 0.f, 0.f, 0.f};
        #pragma unroll
        for (int jt = 0; jt < 2; ++jt) {
            float wp = w_prop[j0 + jt * 16 + lr];
            #pragma unroll
            for (int r = 0; r < 4; ++r) part[r] += acc[jt][r] * wp;
        }
        #pragma unroll
        for (int r = 0; r < 4; ++r) {
            part[r] += __shfl_xor(part[r], 1);
            part[r] += __shfl_xor(part[r], 2);
            part[r] += __shfl_xor(part[r], 4);
            part[r] += __shfl_xor(part[r], 8);
        }
        if (lr == 0) {
            #pragma unroll
            for (int r = 0; r < 4; ++r)
                sred[w * 16 + lg * 4 + r] = part[r];
        }
        __syncthreads();
        if (t < 16) {
            float s = 0.f;
            #pragma unroll
            for (int ww = 0; ww < 8; ++ww) s += sred[ww * 16 + t];
            out[mb * 16 + t] = s + b_prop[0];
        }
    }
}

extern "C" void kernel_launch(void* const* d_in, const int* in_sizes, int n_in,
                              void* d_out, int out_size, void* d_ws, size_t ws_size,
                              hipStream_t stream) {
    const int*   subgraph = (const int*)d_in[0];
    const float* adjm     = (const float*)d_in[2];
    const float* emb      = (const float*)d_in[3];
    const float* w_sub    = (const float*)d_in[4];
    const float* b_sub    = (const float*)d_in[5];
    const float* w_out    = (const float*)d_in[6];
    const float* b_out    = (const float*)d_in[7];
    const float* w_prop   = (const float*)d_in[8];
    const float* b_prop   = (const float*)d_in[9];
    float* outp = (float*)d_out;
    float* gmol = (float*)d_ws;    // 256*256 f32 pooled molecule vectors

    molgnn_layers<<<NMOL, 512, 0, stream>>>(subgraph, adjm, emb, w_sub, b_sub, gmol);
    molgnn_tail<<<16, 512, 0, stream>>>(gmol, w_out, b_out, w_prop, b_prop, outp);
}

// Round 7
// 48.481 us; speedup vs baseline: 1.0420x; 1.0420x over previous
//
#include <hip/hip_runtime.h>

#define NMOL 256
#define VSH 264   // ushort stride, sv hi/lo planes (32 rows x 256 k)
#define TS  40    // ushort stride, shT planes (256 cols x 32 nodes) and adjacency

typedef short bf16x8 __attribute__((ext_vector_type(8)));
typedef float f32x4  __attribute__((ext_vector_type(4)));

__device__ __forceinline__ unsigned short bf_trunc(float f) {
    return (unsigned short)(__float_as_uint(f) >> 16);
}
__device__ __forceinline__ float bf_hif(float f) {
    return __uint_as_float(__float_as_uint(f) & 0xFFFF0000u);
}
__device__ __forceinline__ unsigned short bf_rne(float f) {
    unsigned int u = __float_as_uint(f);
    return (unsigned short)((u + 0x7FFFu + ((u >> 16) & 1u)) >> 16);
}

// split 8 fp32 (two float4) into bf16 hi (trunc) / lo (rne residual) fragments
__device__ __forceinline__ void split8(float4 a, float4 b, bf16x8& hi, bf16x8& lo) {
    float v0[4] = {a.x, a.y, a.z, a.w};
    float v1[4] = {b.x, b.y, b.z, b.w};
    union { unsigned int u[4]; bf16x8 s; } H, L;
    #pragma unroll
    for (int i = 0; i < 2; ++i) {
        unsigned int u0 = __float_as_uint(v0[2*i]), u1 = __float_as_uint(v0[2*i+1]);
        H.u[i] = (u0 >> 16) | (u1 & 0xFFFF0000u);
        unsigned int l0 = bf_rne(v0[2*i]   - __uint_as_float(u0 & 0xFFFF0000u));
        unsigned int l1 = bf_rne(v0[2*i+1] - __uint_as_float(u1 & 0xFFFF0000u));
        L.u[i] = l0 | (l1 << 16);
    }
    #pragma unroll
    for (int i = 0; i < 2; ++i) {
        unsigned int u0 = __float_as_uint(v1[2*i]), u1 = __float_as_uint(v1[2*i+1]);
        H.u[2+i] = (u0 >> 16) | (u1 & 0xFFFF0000u);
        unsigned int l0 = bf_rne(v1[2*i]   - __uint_as_float(u0 & 0xFFFF0000u));
        unsigned int l1 = bf_rne(v1[2*i+1] - __uint_as_float(u1 & 0xFFFF0000u));
        L.u[2+i] = l0 | (l1 << 16);
    }
    hi = H.s; lo = L.s;
}

__launch_bounds__(512, 1)
__global__ void molgnn_mfma(const int* __restrict__ subgraph,
                            const float* __restrict__ adj,
                            const float* __restrict__ emb,
                            const float* __restrict__ w_sub,
                            const float* __restrict__ b_sub,
                            const float* __restrict__ w_out,
                            const float* __restrict__ b_out,
                            const float* __restrict__ w_prop,
                            const float* __restrict__ b_prop,
                            float* __restrict__ out) {
    __shared__ unsigned short svh[32 * VSH];   // v hi plane  [row][k]
    __shared__ unsigned short svl[32 * VSH];   // v lo plane
    __shared__ unsigned short sth[256 * TS];   // h^T hi plane [col][node]
    __shared__ unsigned short stl[256 * TS];   // h^T lo plane
    __shared__ unsigned short sah[32 * TS];    // adjacency block bf16 (exact 0/1)
    __shared__ float srow[8 * 32];
    __shared__ float sinv[32];
    __shared__ float sbias[3 * 256];
    __shared__ float sx[2][256];
    __shared__ float sxp[2][256];
    __shared__ float sred[4];

    const int t = threadIdx.x, m = blockIdx.x;
    const int w  = t >> 6;          // wave 0..7 -> col slab of 32
    const int l  = t & 63;
    const int lr = l & 15;          // frag row/col index
    const int lg = l >> 4;          // frag k-group
    const int j0 = w * 32;

    // W fragment bases (fp32 plane): rows (j0+jt*16+lr), k-offset lg*8
    int bfr[2];
    bfr[0] = (j0 + lr) * 256 + lg * 8;
    bfr[1] = (j0 + 16 + lr) * 256 + lg * 8;

    // ---- early prefetch: layer-0 kt=0 raw fp32 W fragments ----
    float4 Bva[2][2], Bvb[2][2];
    #pragma unroll
    for (int jt = 0; jt < 2; ++jt) {
        Bva[0][jt] = *(const float4*)(w_sub + bfr[jt]);
        Bvb[0][jt] = *(const float4*)(w_sub + bfr[jt] + 4);
    }

    // stage hidden biases
    for (int i = t; i < 768; i += 512) sbias[i] = b_sub[i];

    // gather emb rows -> sv hi/lo planes (16 elems per thread)
    {
        const int r = t >> 4, c0 = (t & 15) * 16;
        const float* src = emb + (long)subgraph[m * 32 + r] * 256 + c0;
        #pragma unroll
        for (int q = 0; q < 16; q += 4) {
            float4 v = *(const float4*)(src + q);
            unsigned int h01 = (unsigned int)bf_trunc(v.x) | ((unsigned int)bf_trunc(v.y) << 16);
            unsigned int h23 = (unsigned int)bf_trunc(v.z) | ((unsigned int)bf_trunc(v.w) << 16);
            unsigned int l01 = (unsigned int)bf_rne(v.x - bf_hif(v.x)) | ((unsigned int)bf_rne(v.y - bf_hif(v.y)) << 16);
            unsigned int l23 = (unsigned int)bf_rne(v.z - bf_hif(v.z)) | ((unsigned int)bf_rne(v.w - bf_hif(v.w)) << 16);
            *(uint2*)&svh[r * VSH + c0 + q] = make_uint2(h01, h23);
            *(uint2*)&svl[r * VSH + c0 + q] = make_uint2(l01, l23);
        }
    }
    // adjacency diag block -> bf16 (0/1 exact under truncation)
    {
        const int r = t >> 4, p0 = (t & 15) * 2;
        const float* ar = adj + (long)(m * 32 + r) * 8192 + m * 32 + p0;
        float2 a = *(const float2*)ar;
        sah[r * TS + p0 + 0] = bf_trunc(a.x);
        sah[r * TS + p0 + 1] = bf_trunc(a.y);
    }
    __syncthreads();

    f32x4 acc[2][2];   // [mt][jt]

    for (int layer = 0; layer < 3; ++layer) {
        // C init = bias[col], broadcast over rows
        #pragma unroll
        for (int jt = 0; jt < 2; ++jt) {
            float b = sbias[layer * 256 + j0 + jt * 16 + lr];
            #pragma unroll
            for (int mt = 0; mt < 2; ++mt) {
                acc[mt][jt][0] = b; acc[mt][jt][1] = b; acc[mt][jt][2] = b; acc[mt][jt][3] = b;
            }
        }

        const float* WP = w_sub + layer * 65536;
        const int nl = (layer < 2) ? layer + 1 : 0;   // layer 2 wraps harmlessly
        const float* WPn = w_sub + nl * 65536;

        // GEMM1: h = v @ W^T  (split bf16, 3 products); raw fp32 W double-buffered,
        // hi/lo split done in-register
        #pragma unroll
        for (int kt = 0; kt < 8; ++kt) {
            const int cur = kt & 1, nxt = cur ^ 1;
            if (kt < 7) {
                #pragma unroll
                for (int jt = 0; jt < 2; ++jt) {
                    Bva[nxt][jt] = *(const float4*)(WP + bfr[jt] + (kt + 1) * 32);
                    Bvb[nxt][jt] = *(const float4*)(WP + bfr[jt] + (kt + 1) * 32 + 4);
                }
            } else {
                #pragma unroll
                for (int jt = 0; jt < 2; ++jt) {
                    Bva[nxt][jt] = *(const float4*)(WPn + bfr[jt]);
                    Bvb[nxt][jt] = *(const float4*)(WPn + bfr[jt] + 4);
                }
            }
            bf16x8 Bh[2], Bl[2];
            #pragma unroll
            for (int jt = 0; jt < 2; ++jt) split8(Bva[cur][jt], Bvb[cur][jt], Bh[jt], Bl[jt]);
            bf16x8 Ah[2], Al[2];
            #pragma unroll
            for (int mt = 0; mt < 2; ++mt) {
                int off = (mt * 16 + lr) * VSH + kt * 32 + lg * 8;
                Ah[mt] = *(const bf16x8*)&svh[off];
                Al[mt] = *(const bf16x8*)&svl[off];
            }
            #pragma unroll
            for (int mt = 0; mt < 2; ++mt)
                #pragma unroll
                for (int jt = 0; jt < 2; ++jt) {
                    acc[mt][jt] = __builtin_amdgcn_mfma_f32_16x16x32_bf16(Ah[mt], Bh[jt], acc[mt][jt], 0, 0, 0);
                    acc[mt][jt] = __builtin_amdgcn_mfma_f32_16x16x32_bf16(Al[mt], Bh[jt], acc[mt][jt], 0, 0, 0);
                    acc[mt][jt] = __builtin_amdgcn_mfma_f32_16x16x32_bf16(Ah[mt], Bl[jt], acc[mt][jt], 0, 0, 0);
                }
        }

        // relu; stage h^T (hi/lo) for this wave's own 32-col slab (no cross-wave use)
        #pragma unroll
        for (int mt = 0; mt < 2; ++mt)
            #pragma unroll
            for (int jt = 0; jt < 2; ++jt) {
                int col = j0 + jt * 16 + lr;
                float hv[4];
                #pragma unroll
                for (int r = 0; r < 4; ++r) {
                    float h = fmaxf(acc[mt][jt][r], 0.f);
                    acc[mt][jt][r] = h;              // residual stays in C
                    hv[r] = h;
                }
                ushort4 hp, lp;
                hp.x = bf_trunc(hv[0]); hp.y = bf_trunc(hv[1]); hp.z = bf_trunc(hv[2]); hp.w = bf_trunc(hv[3]);
                lp.x = bf_rne(hv[0] - bf_hif(hv[0])); lp.y = bf_rne(hv[1] - bf_hif(hv[1]));
                lp.z = bf_rne(hv[2] - bf_hif(hv[2])); lp.w = bf_rne(hv[3] - bf_hif(hv[3]));
                int off = col * TS + mt * 16 + lg * 4;
                *(ushort4*)&sth[off] = hp;
                *(ushort4*)&stl[off] = lp;
            }

        // GEMM2: acc += A @ h  (A exact bf16; h split -> 2 products). Same-wave LDS, no barrier.
        {
            bf16x8 Aa[2];
            #pragma unroll
            for (int mt = 0; mt < 2; ++mt)
                Aa[mt] = *(const bf16x8*)&sah[(mt * 16 + lr) * TS + lg * 8];
            #pragma unroll
            for (int jt = 0; jt < 2; ++jt) {
                int off = (j0 + jt * 16 + lr) * TS + lg * 8;
                bf16x8 Hh = *(const bf16x8*)&sth[off];
                bf16x8 Hl = *(const bf16x8*)&stl[off];
                #pragma unroll
                for (int mt = 0; mt < 2; ++mt) {
                    acc[mt][jt] = __builtin_amdgcn_mfma_f32_16x16x32_bf16(Aa[mt], Hh, acc[mt][jt], 0, 0, 0);
                    acc[mt][jt] = __builtin_amdgcn_mfma_f32_16x16x32_bf16(Aa[mt], Hl, acc[mt][jt], 0, 0, 0);
                }
            }
        }

        // row L2 normalize (rows = mt*16 + lg*4 + r; cols split across lr-lanes and 8 waves)
        float ss[2][4];
        #pragma unroll
        for (int mt = 0; mt < 2; ++mt)
            #pragma unroll
            for (int r = 0; r < 4; ++r) {
                float s = 0.f;
                #pragma unroll
                for (int jt = 0; jt < 2; ++jt) { float a = acc[mt][jt][r]; s += a * a; }
                s += __shfl_xor(s, 1); s += __shfl_xor(s, 2);
                s += __shfl_xor(s, 4); s += __shfl_xor(s, 8);
                ss[mt][r] = s;
            }
        if (lr == 0) {
            #pragma unroll
            for (int mt = 0; mt < 2; ++mt)
                #pragma unroll
                for (int r = 0; r < 4; ++r)
                    srow[w * 32 + mt * 16 + lg * 4 + r] = ss[mt][r];
        }
        __syncthreads();
        if (t < 32) {
            float s = 0.f;
            #pragma unroll
            for (int ww = 0; ww < 8; ++ww) s += srow[ww * 32 + t];
            sinv[t] = 1.0f / fmaxf(sqrtf(s), 1e-12f);
        }
        __syncthreads();
        #pragma unroll
        for (int mt = 0; mt < 2; ++mt)
            #pragma unroll
            for (int r = 0; r < 4; ++r) {
                float iv = sinv[mt * 16 + lg * 4 + r];
                #pragma unroll
                for (int jt = 0; jt < 2; ++jt) acc[mt][jt][r] *= iv;
            }

        if (layer < 2) {
            // write normalized v back as next layer's A planes
            #pragma unroll
            for (int mt = 0; mt < 2; ++mt)
                #pragma unroll
                for (int jt = 0; jt < 2; ++jt) {
                    int col = j0 + jt * 16 + lr;
                    #pragma unroll
                    for (int r = 0; r < 4; ++r) {
                        int row = mt * 16 + lg * 4 + r;
                        float vv = acc[mt][jt][r];
                        svh[row * VSH + col] = bf_trunc(vv);
                        svl[row * VSH + col] = bf_rne(vv - bf_hif(vv));
                    }
                }
            __syncthreads();
        }
    }

    // sum-pool per molecule: col totals (each wave owns its 32 cols)
    #pragma unroll
    for (int jt = 0; jt < 2; ++jt) {
        float s = 0.f;
        #pragma unroll
        for (int mt = 0; mt < 2; ++mt)
            #pragma unroll
            for (int r = 0; r < 4; ++r) s += acc[mt][jt][r];
        s += __shfl_xor(s, 16);
        s += __shfl_xor(s, 32);
        if (l < 16) sx[0][j0 + jt * 16 + l] = s;
    }
    __syncthreads();

    // output MLP (fp32, exact): col = t&255, split-k over 2 halves
    {
        const int col = t & 255, half = t >> 8;
        int cur = 0;
        for (int ol = 0; ol < 2; ++ol) {
            const float* Wr = w_out + (long)ol * 65536 + (long)col * 256 + half * 128;
            const float* xs = &sx[cur][half * 128];
            float s = 0.f;
            #pragma unroll 8
            for (int k = 0; k < 128; k += 4) {
                float4 w4 = *(const float4*)(Wr + k);
                s += w4.x * xs[k + 0] + w4.y * xs[k + 1]
                   + w4.z * xs[k + 2] + w4.w * xs[k + 3];
            }
            sxp[half][col] = s;
            __syncthreads();
            if (half == 0) {
                float v = sxp[0][col] + sxp[1][col] + b_out[ol * 256 + col];
                sx[1 - cur][col] = fmaxf(v, 0.f);
            }
            __syncthreads();
            cur = 1 - cur;
        }

        // property head (final x is in sx[0])
        float p = 0.f;
        if (t < 256) p = sx[0][t] * w_prop[t];
        #pragma unroll
        for (int off = 1; off < 64; off <<= 1) p += __shfl_xor(p, off);
        if (t < 256 && (t & 63) == 0) sred[t >> 6] = p;
        __syncthreads();
        if (t == 0) out[m] = sred[0] + sred[1] + sred[2] + sred[3] + b_prop[0];
    }
}

extern "C" void kernel_launch(void* const* d_in, const int* in_sizes, int n_in,
                              void* d_out, int out_size, void* d_ws, size_t ws_size,
                              hipStream_t stream) {
    const int*   subgraph = (const int*)d_in[0];
    const float* adjm     = (const float*)d_in[2];
    const float* emb      = (const float*)d_in[3];
    const float* w_sub    = (const float*)d_in[4];
    const float* b_sub    = (const float*)d_in[5];
    const float* w_out    = (const float*)d_in[6];
    const float* b_out    = (const float*)d_in[7];
    const float* w_prop   = (const float*)d_in[8];
    const float* b_prop   = (const float*)d_in[9];
    float* outp = (float*)d_out;

    molgnn_mfma<<<NMOL, 512, 0, stream>>>(subgraph, adjm, emb, w_sub, b_sub,
                                          w_out, b_out, w_prop, b_prop, outp);
}

// Round 8
// 47.046 us; speedup vs baseline: 1.0738x; 1.0305x over previous
//
#include <hip/hip_runtime.h>

#define NMOL 256
#define VSH 264   // ushort stride, sv hi/lo planes (32 rows x 256 k)
#define TS  40    // ushort stride, shT planes (256 cols x 32 nodes) and adjacency

typedef short bf16x8 __attribute__((ext_vector_type(8)));
typedef float f32x4  __attribute__((ext_vector_type(4)));

__device__ __forceinline__ unsigned short bf_trunc(float f) {
    return (unsigned short)(__float_as_uint(f) >> 16);
}
__device__ __forceinline__ float bf_hif(float f) {
    return __uint_as_float(__float_as_uint(f) & 0xFFFF0000u);
}
__device__ __forceinline__ unsigned short bf_rne(float f) {
    unsigned int u = __float_as_uint(f);
    return (unsigned short)((u + 0x7FFFu + ((u >> 16) & 1u)) >> 16);
}

// packed f32x2 -> bf16x2 (RNE), low 16 bits = first operand (T12 recipe, gfx950)
__device__ __forceinline__ unsigned int cvt_pk_bf16(float lo, float hi) {
    unsigned int r;
    asm("v_cvt_pk_bf16_f32 %0, %1, %2" : "=v"(r) : "v"(lo), "v"(hi));
    return r;
}

// split 8 fp32 (two float4) into bf16 hi (rne) / lo (rne residual) fragments via cvt_pk
__device__ __forceinline__ void split8(float4 a, float4 b, bf16x8& hi, bf16x8& lo) {
    float f[8] = {a.x, a.y, a.z, a.w, b.x, b.y, b.z, b.w};
    union { unsigned int u[4]; bf16x8 s; } H, L;
    #pragma unroll
    for (int i = 0; i < 4; ++i) {
        unsigned int h = cvt_pk_bf16(f[2*i], f[2*i+1]);
        H.u[i] = h;
        float hf0 = __uint_as_float(h << 16);
        float hf1 = __uint_as_float(h & 0xFFFF0000u);
        L.u[i] = cvt_pk_bf16(f[2*i] - hf0, f[2*i+1] - hf1);
    }
    hi = H.s; lo = L.s;
}

__launch_bounds__(512, 1)
__global__ void molgnn_mfma(const int* __restrict__ subgraph,
                            const float* __restrict__ adj,
                            const float* __restrict__ emb,
                            const float* __restrict__ w_sub,
                            const float* __restrict__ b_sub,
                            const float* __restrict__ w_out,
                            const float* __restrict__ b_out,
                            const float* __restrict__ w_prop,
                            const float* __restrict__ b_prop,
                            float* __restrict__ out) {
    __shared__ unsigned short svh[32 * VSH];   // v hi plane  [row][k]
    __shared__ unsigned short svl[32 * VSH];   // v lo plane
    __shared__ unsigned short sth[256 * TS];   // h^T hi plane [col][node]
    __shared__ unsigned short stl[256 * TS];   // h^T lo plane
    __shared__ unsigned short sah[32 * TS];    // adjacency block bf16 (exact 0/1)
    __shared__ float srow[8 * 32];
    __shared__ float sinv[32];
    __shared__ float sbias[3 * 256];
    __shared__ float sx[2][256];
    __shared__ float sxp[2][256];
    __shared__ float sred[4];

    const int t = threadIdx.x, m = blockIdx.x;
    const int w  = t >> 6;          // wave 0..7 -> col slab of 32
    const int l  = t & 63;
    const int lr = l & 15;          // frag row/col index
    const int lg = l >> 4;          // frag k-group
    const int j0 = w * 32;

    // W fragment bases (fp32 plane): rows (j0+jt*16+lr), k-offset lg*8
    int bfr[2];
    bfr[0] = (j0 + lr) * 256 + lg * 8;
    bfr[1] = (j0 + 16 + lr) * 256 + lg * 8;

    // ---- early prefetch: layer-0 kt=0 raw fp32 W fragments ----
    float4 Bva[2][2], Bvb[2][2];
    #pragma unroll
    for (int jt = 0; jt < 2; ++jt) {
        Bva[0][jt] = *(const float4*)(w_sub + bfr[jt]);
        Bvb[0][jt] = *(const float4*)(w_sub + bfr[jt] + 4);
    }

    // stage hidden biases
    for (int i = t; i < 768; i += 512) sbias[i] = b_sub[i];

    // gather emb rows -> sv hi/lo planes (16 elems per thread), cvt_pk packing
    {
        const int r = t >> 4, c0 = (t & 15) * 16;
        const float* src = emb + (long)subgraph[m * 32 + r] * 256 + c0;
        #pragma unroll
        for (int q = 0; q < 16; q += 4) {
            float4 v = *(const float4*)(src + q);
            unsigned int h01 = cvt_pk_bf16(v.x, v.y);
            unsigned int h23 = cvt_pk_bf16(v.z, v.w);
            float l0 = v.x - __uint_as_float(h01 << 16);
            float l1 = v.y - __uint_as_float(h01 & 0xFFFF0000u);
            float l2 = v.z - __uint_as_float(h23 << 16);
            float l3 = v.w - __uint_as_float(h23 & 0xFFFF0000u);
            unsigned int l01 = cvt_pk_bf16(l0, l1);
            unsigned int l23 = cvt_pk_bf16(l2, l3);
            *(uint2*)&svh[r * VSH + c0 + q] = make_uint2(h01, h23);
            *(uint2*)&svl[r * VSH + c0 + q] = make_uint2(l01, l23);
        }
    }
    // adjacency diag block -> bf16 (0/1 exact under RNE), cvt_pk pair
    {
        const int r = t >> 4, p0 = (t & 15) * 2;
        const float* ar = adj + (long)(m * 32 + r) * 8192 + m * 32 + p0;
        float2 a = *(const float2*)ar;
        *(unsigned int*)&sah[r * TS + p0] = cvt_pk_bf16(a.x, a.y);
    }
    __syncthreads();

    f32x4 acc[2][2];   // [mt][jt]

    for (int layer = 0; layer < 3; ++layer) {
        // C init = bias[col], broadcast over rows
        #pragma unroll
        for (int jt = 0; jt < 2; ++jt) {
            float b = sbias[layer * 256 + j0 + jt * 16 + lr];
            #pragma unroll
            for (int mt = 0; mt < 2; ++mt) {
                acc[mt][jt][0] = b; acc[mt][jt][1] = b; acc[mt][jt][2] = b; acc[mt][jt][3] = b;
            }
        }

        const float* WP = w_sub + layer * 65536;
        const int nl = (layer < 2) ? layer + 1 : 0;   // layer 2 wraps harmlessly
        const float* WPn = w_sub + nl * 65536;

        // GEMM1: h = v @ W^T  (split bf16, 3 products); raw fp32 W double-buffered,
        // hi/lo split in-register via v_cvt_pk_bf16_f32
        #pragma unroll
        for (int kt = 0; kt < 8; ++kt) {
            const int cur = kt & 1, nxt = cur ^ 1;
            if (kt < 7) {
                #pragma unroll
                for (int jt = 0; jt < 2; ++jt) {
                    Bva[nxt][jt] = *(const float4*)(WP + bfr[jt] + (kt + 1) * 32);
                    Bvb[nxt][jt] = *(const float4*)(WP + bfr[jt] + (kt + 1) * 32 + 4);
                }
            } else {
                #pragma unroll
                for (int jt = 0; jt < 2; ++jt) {
                    Bva[nxt][jt] = *(const float4*)(WPn + bfr[jt]);
                    Bvb[nxt][jt] = *(const float4*)(WPn + bfr[jt] + 4);
                }
            }
            bf16x8 Bh[2], Bl[2];
            #pragma unroll
            for (int jt = 0; jt < 2; ++jt) split8(Bva[cur][jt], Bvb[cur][jt], Bh[jt], Bl[jt]);
            bf16x8 Ah[2], Al[2];
            #pragma unroll
            for (int mt = 0; mt < 2; ++mt) {
                int off = (mt * 16 + lr) * VSH + kt * 32 + lg * 8;
                Ah[mt] = *(const bf16x8*)&svh[off];
                Al[mt] = *(const bf16x8*)&svl[off];
            }
            #pragma unroll
            for (int mt = 0; mt < 2; ++mt)
                #pragma unroll
                for (int jt = 0; jt < 2; ++jt) {
                    acc[mt][jt] = __builtin_amdgcn_mfma_f32_16x16x32_bf16(Ah[mt], Bh[jt], acc[mt][jt], 0, 0, 0);
                    acc[mt][jt] = __builtin_amdgcn_mfma_f32_16x16x32_bf16(Al[mt], Bh[jt], acc[mt][jt], 0, 0, 0);
                    acc[mt][jt] = __builtin_amdgcn_mfma_f32_16x16x32_bf16(Ah[mt], Bl[jt], acc[mt][jt], 0, 0, 0);
                }
        }

        // relu; stage h^T (hi/lo) for this wave's own 32-col slab (cvt_pk packing)
        #pragma unroll
        for (int mt = 0; mt < 2; ++mt)
            #pragma unroll
            for (int jt = 0; jt < 2; ++jt) {
                int col = j0 + jt * 16 + lr;
                float hv[4];
                #pragma unroll
                for (int r = 0; r < 4; ++r) {
                    float h = fmaxf(acc[mt][jt][r], 0.f);
                    acc[mt][jt][r] = h;              // residual stays in C
                    hv[r] = h;
                }
                unsigned int hp01 = cvt_pk_bf16(hv[0], hv[1]);
                unsigned int hp23 = cvt_pk_bf16(hv[2], hv[3]);
                float lo0 = hv[0] - __uint_as_float(hp01 << 16);
                float lo1 = hv[1] - __uint_as_float(hp01 & 0xFFFF0000u);
                float lo2 = hv[2] - __uint_as_float(hp23 << 16);
                float lo3 = hv[3] - __uint_as_float(hp23 & 0xFFFF0000u);
                unsigned int lp01 = cvt_pk_bf16(lo0, lo1);
                unsigned int lp23 = cvt_pk_bf16(lo2, lo3);
                int off = col * TS + mt * 16 + lg * 4;
                *(uint2*)&sth[off] = make_uint2(hp01, hp23);
                *(uint2*)&stl[off] = make_uint2(lp01, lp23);
            }

        // GEMM2: acc += A @ h  (A exact bf16; h split -> 2 products). Same-wave LDS, no barrier.
        {
            bf16x8 Aa[2];
            #pragma unroll
            for (int mt = 0; mt < 2; ++mt)
                Aa[mt] = *(const bf16x8*)&sah[(mt * 16 + lr) * TS + lg * 8];
            #pragma unroll
            for (int jt = 0; jt < 2; ++jt) {
                int off = (j0 + jt * 16 + lr) * TS + lg * 8;
                bf16x8 Hh = *(const bf16x8*)&sth[off];
                bf16x8 Hl = *(const bf16x8*)&stl[off];
                #pragma unroll
                for (int mt = 0; mt < 2; ++mt) {
                    acc[mt][jt] = __builtin_amdgcn_mfma_f32_16x16x32_bf16(Aa[mt], Hh, acc[mt][jt], 0, 0, 0);
                    acc[mt][jt] = __builtin_amdgcn_mfma_f32_16x16x32_bf16(Aa[mt], Hl, acc[mt][jt], 0, 0, 0);
                }
            }
        }

        // row L2 normalize (rows = mt*16 + lg*4 + r; cols split across lr-lanes and 8 waves)
        float ss[2][4];
        #pragma unroll
        for (int mt = 0; mt < 2; ++mt)
            #pragma unroll
            for (int r = 0; r < 4; ++r) {
                float s = 0.f;
                #pragma unroll
                for (int jt = 0; jt < 2; ++jt) { float a = acc[mt][jt][r]; s += a * a; }
                s += __shfl_xor(s, 1); s += __shfl_xor(s, 2);
                s += __shfl_xor(s, 4); s += __shfl_xor(s, 8);
                ss[mt][r] = s;
            }
        if (lr == 0) {
            #pragma unroll
            for (int mt = 0; mt < 2; ++mt)
                #pragma unroll
                for (int r = 0; r < 4; ++r)
                    srow[w * 32 + mt * 16 + lg * 4 + r] = ss[mt][r];
        }
        __syncthreads();
        if (t < 32) {
            float s = 0.f;
            #pragma unroll
            for (int ww = 0; ww < 8; ++ww) s += srow[ww * 32 + t];
            sinv[t] = 1.0f / fmaxf(sqrtf(s), 1e-12f);
        }
        __syncthreads();
        #pragma unroll
        for (int mt = 0; mt < 2; ++mt)
            #pragma unroll
            for (int r = 0; r < 4; ++r) {
                float iv = sinv[mt * 16 + lg * 4 + r];
                #pragma unroll
                for (int jt = 0; jt < 2; ++jt) acc[mt][jt][r] *= iv;
            }

        if (layer < 2) {
            // write normalized v back as next layer's A planes (scalar, true k-order)
            #pragma unroll
            for (int mt = 0; mt < 2; ++mt)
                #pragma unroll
                for (int jt = 0; jt < 2; ++jt) {
                    int col = j0 + jt * 16 + lr;
                    #pragma unroll
                    for (int r = 0; r < 4; ++r) {
                        int row = mt * 16 + lg * 4 + r;
                        float vv = acc[mt][jt][r];
                        svh[row * VSH + col] = bf_trunc(vv);
                        svl[row * VSH + col] = bf_rne(vv - bf_hif(vv));
                    }
                }
            __syncthreads();
        }
    }

    // sum-pool per molecule: col totals (each wave owns its 32 cols)
    #pragma unroll
    for (int jt = 0; jt < 2; ++jt) {
        float s = 0.f;
        #pragma unroll
        for (int mt = 0; mt < 2; ++mt)
            #pragma unroll
            for (int r = 0; r < 4; ++r) s += acc[mt][jt][r];
        s += __shfl_xor(s, 16);
        s += __shfl_xor(s, 32);
        if (l < 16) sx[0][j0 + jt * 16 + l] = s;
    }
    __syncthreads();

    // output MLP (fp32, exact): col = t&255, split-k over 2 halves
    {
        const int col = t & 255, half = t >> 8;
        int cur = 0;
        for (int ol = 0; ol < 2; ++ol) {
            const float* Wr = w_out + (long)ol * 65536 + (long)col * 256 + half * 128;
            const float* xs = &sx[cur][half * 128];
            float s = 0.f;
            #pragma unroll 8
            for (int k = 0; k < 128; k += 4) {
                float4 w4 = *(const float4*)(Wr + k);
                s += w4.x * xs[k + 0] + w4.y * xs[k + 1]
                   + w4.z * xs[k + 2] + w4.w * xs[k + 3];
            }
            sxp[half][col] = s;
            __syncthreads();
            if (half == 0) {
                float v = sxp[0][col] + sxp[1][col] + b_out[ol * 256 + col];
                sx[1 - cur][col] = fmaxf(v, 0.f);
            }
            __syncthreads();
            cur = 1 - cur;
        }

        // property head (final x is in sx[0])
        float p = 0.f;
        if (t < 256) p = sx[0][t] * w_prop[t];
        #pragma unroll
        for (int off = 1; off < 64; off <<= 1) p += __shfl_xor(p, off);
        if (t < 256 && (t & 63) == 0) sred[t >> 6] = p;
        __syncthreads();
        if (t == 0) out[m] = sred[0] + sred[1] + sred[2] + sred[3] + b_prop[0];
    }
}

extern "C" void kernel_launch(void* const* d_in, const int* in_sizes, int n_in,
                              void* d_out, int out_size, void* d_ws, size_t ws_size,
                              hipStream_t stream) {
    const int*   subgraph = (const int*)d_in[0];
    const float* adjm     = (const float*)d_in[2];
    const float* emb      = (const float*)d_in[3];
    const float* w_sub    = (const float*)d_in[4];
    const float* b_sub    = (const float*)d_in[5];
    const float* w_out    = (const float*)d_in[6];
    const float* b_out    = (const float*)d_in[7];
    const float* w_prop   = (const float*)d_in[8];
    const float* b_prop   = (const float*)d_in[9];
    float* outp = (float*)d_out;

    molgnn_mfma<<<NMOL, 512, 0, stream>>>(subgraph, adjm, emb, w_sub, b_sub,
                                          w_out, b_out, w_prop, b_prop, outp);
}

// Round 9
// 46.041 us; speedup vs baseline: 1.0972x; 1.0218x over previous
//
#include <hip/hip_runtime.h>

#define NMOL 256
#define VSH 264   // ushort stride, sv hi/lo planes (32 rows x 256 k)
#define TS  40    // ushort stride, shT planes (256 cols x 32 nodes) and adjacency

typedef short bf16x8 __attribute__((ext_vector_type(8)));
typedef float f32x4  __attribute__((ext_vector_type(4)));

__device__ __forceinline__ unsigned short bf_trunc(float f) {
    return (unsigned short)(__float_as_uint(f) >> 16);
}
__device__ __forceinline__ float bf_hif(float f) {
    return __uint_as_float(__float_as_uint(f) & 0xFFFF0000u);
}
__device__ __forceinline__ unsigned short bf_rne(float f) {
    unsigned int u = __float_as_uint(f);
    return (unsigned short)((u + 0x7FFFu + ((u >> 16) & 1u)) >> 16);
}

// packed f32x2 -> bf16x2 (RNE), low 16 bits = first operand
__device__ __forceinline__ unsigned int cvt_pk_bf16(float lo, float hi) {
    unsigned int r;
    asm("v_cvt_pk_bf16_f32 %0, %1, %2" : "=v"(r) : "v"(lo), "v"(hi));
    return r;
}

// split 8 fp32 (two float4) into bf16 hi (rne) / lo (rne residual) fragments via cvt_pk
__device__ __forceinline__ void split8(float4 a, float4 b, bf16x8& hi, bf16x8& lo) {
    float f[8] = {a.x, a.y, a.z, a.w, b.x, b.y, b.z, b.w};
    union { unsigned int u[4]; bf16x8 s; } H, L;
    #pragma unroll
    for (int i = 0; i < 4; ++i) {
        unsigned int h = cvt_pk_bf16(f[2*i], f[2*i+1]);
        H.u[i] = h;
        float hf0 = __uint_as_float(h << 16);
        float hf1 = __uint_as_float(h & 0xFFFF0000u);
        L.u[i] = cvt_pk_bf16(f[2*i] - hf0, f[2*i+1] - hf1);
    }
    hi = H.s; lo = L.s;
}

__launch_bounds__(512, 1)
__global__ void molgnn_mfma(const int* __restrict__ subgraph,
                            const float* __restrict__ adj,
                            const float* __restrict__ emb,
                            const float* __restrict__ w_sub,
                            const float* __restrict__ b_sub,
                            const float* __restrict__ w_out,
                            const float* __restrict__ b_out,
                            const float* __restrict__ w_prop,
                            const float* __restrict__ b_prop,
                            float* __restrict__ out) {
    __shared__ unsigned short svh[32 * VSH];   // v hi plane  [row][k]
    __shared__ unsigned short svl[32 * VSH];   // v lo plane
    __shared__ unsigned short sth[256 * TS];   // h^T hi plane [col][node]
    __shared__ unsigned short stl[256 * TS];   // h^T lo plane
    __shared__ unsigned short sah[32 * TS];    // adjacency block bf16 (exact 0/1)
    __shared__ float srow[8 * 32];
    __shared__ float sinv[32];
    __shared__ float sbias[3 * 256];
    __shared__ float sx[2][256];
    __shared__ float sxp[2][256];
    __shared__ float sred[4];

    const int t = threadIdx.x, m = blockIdx.x;
    const int w  = t >> 6;          // wave 0..7 -> col slab of 32
    const int l  = t & 63;
    const int lr = l & 15;          // frag row/col index
    const int lg = l >> 4;          // frag k-group
    const int j0 = w * 32;

    // W fragment bases (fp32 plane): rows (j0+jt*16+lr), k-offset lg*8
    int bfr[2];
    bfr[0] = (j0 + lr) * 256 + lg * 8;
    bfr[1] = (j0 + 16 + lr) * 256 + lg * 8;

    // ---- depth-3 W prefetch pipeline over global steps s = layer*8 + kt ----
    // slot(s) = s % 3; seed s=0,1 right at kernel top (8 loads in flight).
    float4 Bva[3][2], Bvb[3][2];
    #pragma unroll
    for (int jt = 0; jt < 2; ++jt) {
        Bva[0][jt] = *(const float4*)(w_sub + bfr[jt]);               // s=0 (l0,kt0)
        Bvb[0][jt] = *(const float4*)(w_sub + bfr[jt] + 4);
        Bva[1][jt] = *(const float4*)(w_sub + bfr[jt] + 32);          // s=1 (l0,kt1)
        Bvb[1][jt] = *(const float4*)(w_sub + bfr[jt] + 32 + 4);
    }

    // stage hidden biases
    for (int i = t; i < 768; i += 512) sbias[i] = b_sub[i];

    // gather emb rows -> sv hi/lo planes (16 elems per thread), cvt_pk packing
    {
        const int r = t >> 4, c0 = (t & 15) * 16;
        const float* src = emb + (long)subgraph[m * 32 + r] * 256 + c0;
        #pragma unroll
        for (int q = 0; q < 16; q += 4) {
            float4 v = *(const float4*)(src + q);
            unsigned int h01 = cvt_pk_bf16(v.x, v.y);
            unsigned int h23 = cvt_pk_bf16(v.z, v.w);
            float l0 = v.x - __uint_as_float(h01 << 16);
            float l1 = v.y - __uint_as_float(h01 & 0xFFFF0000u);
            float l2 = v.z - __uint_as_float(h23 << 16);
            float l3 = v.w - __uint_as_float(h23 & 0xFFFF0000u);
            unsigned int l01 = cvt_pk_bf16(l0, l1);
            unsigned int l23 = cvt_pk_bf16(l2, l3);
            *(uint2*)&svh[r * VSH + c0 + q] = make_uint2(h01, h23);
            *(uint2*)&svl[r * VSH + c0 + q] = make_uint2(l01, l23);
        }
    }
    // adjacency diag block -> bf16 (0/1 exact under RNE), cvt_pk pair
    {
        const int r = t >> 4, p0 = (t & 15) * 2;
        const float* ar = adj + (long)(m * 32 + r) * 8192 + m * 32 + p0;
        float2 a = *(const float2*)ar;
        *(unsigned int*)&sah[r * TS + p0] = cvt_pk_bf16(a.x, a.y);
    }
    __syncthreads();

    f32x4 acc[2][2];   // [mt][jt]

    #pragma unroll
    for (int layer = 0; layer < 3; ++layer) {
        // C init = bias[col], broadcast over rows
        #pragma unroll
        for (int jt = 0; jt < 2; ++jt) {
            float b = sbias[layer * 256 + j0 + jt * 16 + lr];
            #pragma unroll
            for (int mt = 0; mt < 2; ++mt) {
                acc[mt][jt][0] = b; acc[mt][jt][1] = b; acc[mt][jt][2] = b; acc[mt][jt][3] = b;
            }
        }

        // ---- A-fragment depth-2 prefetch: kt=0 ----
        bf16x8 Ah[2][2], Al[2][2];   // [buf][mt]
        #pragma unroll
        for (int mt = 0; mt < 2; ++mt) {
            int off = (mt * 16 + lr) * VSH + lg * 8;
            Ah[0][mt] = *(const bf16x8*)&svh[off];
            Al[0][mt] = *(const bf16x8*)&svl[off];
        }

        // GEMM1: h = v @ W^T  (split bf16, 3 products)
        #pragma unroll
        for (int kt = 0; kt < 8; ++kt) {
            const int s    = layer * 8 + kt;
            const int cur  = s % 3;
            const int s2   = (s + 2) % 24;          // wraps to layer 0 after the end (harmless)
            const int slot = (s + 2) % 3;
            const int abuf = kt & 1, anxt = abuf ^ 1;
            // issue W loads for step s+2
            {
                const float* WA = w_sub + (s2 >> 3) * 65536 + (s2 & 7) * 32;
                #pragma unroll
                for (int jt = 0; jt < 2; ++jt) {
                    Bva[slot][jt] = *(const float4*)(WA + bfr[jt]);
                    Bvb[slot][jt] = *(const float4*)(WA + bfr[jt] + 4);
                }
            }
            // issue A ds_reads for kt+1
            if (kt < 7) {
                #pragma unroll
                for (int mt = 0; mt < 2; ++mt) {
                    int off = (mt * 16 + lr) * VSH + (kt + 1) * 32 + lg * 8;
                    Ah[anxt][mt] = *(const bf16x8*)&svh[off];
                    Al[anxt][mt] = *(const bf16x8*)&svl[off];
                }
            }
            bf16x8 Bh[2], Bl[2];
            #pragma unroll
            for (int jt = 0; jt < 2; ++jt) split8(Bva[cur][jt], Bvb[cur][jt], Bh[jt], Bl[jt]);
            __builtin_amdgcn_s_setprio(1);
            #pragma unroll
            for (int mt = 0; mt < 2; ++mt)
                #pragma unroll
                for (int jt = 0; jt < 2; ++jt) {
                    acc[mt][jt] = __builtin_amdgcn_mfma_f32_16x16x32_bf16(Ah[abuf][mt], Bh[jt], acc[mt][jt], 0, 0, 0);
                    acc[mt][jt] = __builtin_amdgcn_mfma_f32_16x16x32_bf16(Al[abuf][mt], Bh[jt], acc[mt][jt], 0, 0, 0);
                    acc[mt][jt] = __builtin_amdgcn_mfma_f32_16x16x32_bf16(Ah[abuf][mt], Bl[jt], acc[mt][jt], 0, 0, 0);
                }
            __builtin_amdgcn_s_setprio(0);
        }

        // relu; stage h^T (hi/lo) for this wave's own 32-col slab (cvt_pk packing)
        #pragma unroll
        for (int mt = 0; mt < 2; ++mt)
            #pragma unroll
            for (int jt = 0; jt < 2; ++jt) {
                int col = j0 + jt * 16 + lr;
                float hv[4];
                #pragma unroll
                for (int r = 0; r < 4; ++r) {
                    float h = fmaxf(acc[mt][jt][r], 0.f);
                    acc[mt][jt][r] = h;              // residual stays in C
                    hv[r] = h;
                }
                unsigned int hp01 = cvt_pk_bf16(hv[0], hv[1]);
                unsigned int hp23 = cvt_pk_bf16(hv[2], hv[3]);
                float lo0 = hv[0] - __uint_as_float(hp01 << 16);
                float lo1 = hv[1] - __uint_as_float(hp01 & 0xFFFF0000u);
                float lo2 = hv[2] - __uint_as_float(hp23 << 16);
                float lo3 = hv[3] - __uint_as_float(hp23 & 0xFFFF0000u);
                unsigned int lp01 = cvt_pk_bf16(lo0, lo1);
                unsigned int lp23 = cvt_pk_bf16(lo2, lo3);
                int off = col * TS + mt * 16 + lg * 4;
                *(uint2*)&sth[off] = make_uint2(hp01, hp23);
                *(uint2*)&stl[off] = make_uint2(lp01, lp23);
            }

        // GEMM2: acc += A @ h  (A exact bf16; h split -> 2 products). Same-wave LDS, no barrier.
        {
            bf16x8 Aa[2];
            #pragma unroll
            for (int mt = 0; mt < 2; ++mt)
                Aa[mt] = *(const bf16x8*)&sah[(mt * 16 + lr) * TS + lg * 8];
            #pragma unroll
            for (int jt = 0; jt < 2; ++jt) {
                int off = (j0 + jt * 16 + lr) * TS + lg * 8;
                bf16x8 Hh = *(const bf16x8*)&sth[off];
                bf16x8 Hl = *(const bf16x8*)&stl[off];
                __builtin_amdgcn_s_setprio(1);
                #pragma unroll
                for (int mt = 0; mt < 2; ++mt) {
                    acc[mt][jt] = __builtin_amdgcn_mfma_f32_16x16x32_bf16(Aa[mt], Hh, acc[mt][jt], 0, 0, 0);
                    acc[mt][jt] = __builtin_amdgcn_mfma_f32_16x16x32_bf16(Aa[mt], Hl, acc[mt][jt], 0, 0, 0);
                }
                __builtin_amdgcn_s_setprio(0);
            }
        }

        // row L2 normalize (rows = mt*16 + lg*4 + r; cols split across lr-lanes and 8 waves)
        float ss[2][4];
        #pragma unroll
        for (int mt = 0; mt < 2; ++mt)
            #pragma unroll
            for (int r = 0; r < 4; ++r) {
                float s = 0.f;
                #pragma unroll
                for (int jt = 0; jt < 2; ++jt) { float a = acc[mt][jt][r]; s += a * a; }
                s += __shfl_xor(s, 1); s += __shfl_xor(s, 2);
                s += __shfl_xor(s, 4); s += __shfl_xor(s, 8);
                ss[mt][r] = s;
            }
        if (lr == 0) {
            #pragma unroll
            for (int mt = 0; mt < 2; ++mt)
                #pragma unroll
                for (int r = 0; r < 4; ++r)
                    srow[w * 32 + mt * 16 + lg * 4 + r] = ss[mt][r];
        }
        __syncthreads();
        if (t < 32) {
            float s = 0.f;
            #pragma unroll
            for (int ww = 0; ww < 8; ++ww) s += srow[ww * 32 + t];
            sinv[t] = 1.0f / fmaxf(sqrtf(s), 1e-12f);
        }
        __syncthreads();
        #pragma unroll
        for (int mt = 0; mt < 2; ++mt)
            #pragma unroll
            for (int r = 0; r < 4; ++r) {
                float iv = sinv[mt * 16 + lg * 4 + r];
                #pragma unroll
                for (int jt = 0; jt < 2; ++jt) acc[mt][jt][r] *= iv;
            }

        if (layer < 2) {
            // write normalized v back as next layer's A planes
            #pragma unroll
            for (int mt = 0; mt < 2; ++mt)
                #pragma unroll
                for (int jt = 0; jt < 2; ++jt) {
                    int col = j0 + jt * 16 + lr;
                    #pragma unroll
                    for (int r = 0; r < 4; ++r) {
                        int row = mt * 16 + lg * 4 + r;
                        float vv = acc[mt][jt][r];
                        svh[row * VSH + col] = bf_trunc(vv);
                        svl[row * VSH + col] = bf_rne(vv - bf_hif(vv));
                    }
                }
            __syncthreads();
        }
    }

    // sum-pool per molecule: col totals (each wave owns its 32 cols)
    #pragma unroll
    for (int jt = 0; jt < 2; ++jt) {
        float s = 0.f;
        #pragma unroll
        for (int mt = 0; mt < 2; ++mt)
            #pragma unroll
            for (int r = 0; r < 4; ++r) s += acc[mt][jt][r];
        s += __shfl_xor(s, 16);
        s += __shfl_xor(s, 32);
        if (l < 16) sx[0][j0 + jt * 16 + l] = s;
    }
    __syncthreads();

    // output MLP (fp32, exact): col = t&255, split-k over 2 halves
    {
        const int col = t & 255, half = t >> 8;
        int cur = 0;
        for (int ol = 0; ol < 2; ++ol) {
            const float* Wr = w_out + (long)ol * 65536 + (long)col * 256 + half * 128;
            const float* xs = &sx[cur][half * 128];
            float s = 0.f;
            #pragma unroll 8
            for (int k = 0; k < 128; k += 4) {
                float4 w4 = *(const float4*)(Wr + k);
                s += w4.x * xs[k + 0] + w4.y * xs[k + 1]
                   + w4.z * xs[k + 2] + w4.w * xs[k + 3];
            }
            sxp[half][col] = s;
            __syncthreads();
            if (half == 0) {
                float v = sxp[0][col] + sxp[1][col] + b_out[ol * 256 + col];
                sx[1 - cur][col] = fmaxf(v, 0.f);
            }
            __syncthreads();
            cur = 1 - cur;
        }

        // property head (final x is in sx[0])
        float p = 0.f;
        if (t < 256) p = sx[0][t] * w_prop[t];
        #pragma unroll
        for (int off = 1; off < 64; off <<= 1) p += __shfl_xor(p, off);
        if (t < 256 && (t & 63) == 0) sred[t >> 6] = p;
        __syncthreads();
        if (t == 0) out[m] = sred[0] + sred[1] + sred[2] + sred[3] + b_prop[0];
    }
}

extern "C" void kernel_launch(void* const* d_in, const int* in_sizes, int n_in,
                              void* d_out, int out_size, void* d_ws, size_t ws_size,
                              hipStream_t stream) {
    const int*   subgraph = (const int*)d_in[0];
    const float* adjm     = (const float*)d_in[2];
    const float* emb      = (const float*)d_in[3];
    const float* w_sub    = (const float*)d_in[4];
    const float* b_sub    = (const float*)d_in[5];
    const float* w_out    = (const float*)d_in[6];
    const float* b_out    = (const float*)d_in[7];
    const float* w_prop   = (const float*)d_in[8];
    const float* b_prop   = (const float*)d_in[9];
    float* outp = (float*)d_out;

    molgnn_mfma<<<NMOL, 512, 0, stream>>>(subgraph, adjm, emb, w_sub, b_sub,
                                          w_out, b_out, w_prop, b_prop, outp);
}